// Round 1
// baseline (1050.753 us; speedup 1.0000x reference)
//
#include <hip/hip_runtime.h>

#define S3  1.7320508075688772f
#define S5  2.23606797749979f
#define S15 3.872983346207417f

__device__ __forceinline__ float silu_f(float x) {
    return x / (1.0f + __expf(-x));
}

__device__ __forceinline__ void fma4(float4& a, float s, float4 v) {
    a.x = fmaf(s, v.x, a.x);
    a.y = fmaf(s, v.y, a.y);
    a.z = fmaf(s, v.z, a.z);
    a.w = fmaf(s, v.w, a.w);
}

// ---------------------------------------------------------------------------
// Node MLP: Ai = (silu(silu(emb[A] @ W1 + b1) @ W2 + b2)) @ W3 + b3   (N x 8)
// ---------------------------------------------------------------------------
__global__ __launch_bounds__(256) void node_mlp_kernel(
    const float* __restrict__ emb_table,  // 10x16
    const float* __restrict__ W1, const float* __restrict__ b1,  // 16x64
    const float* __restrict__ W2, const float* __restrict__ b2,  // 64x32
    const float* __restrict__ W3, const float* __restrict__ b3,  // 32x8
    const int*   __restrict__ A,
    float* __restrict__ Ai, int N)
{
    __shared__ float sE[160];
    __shared__ float sW1[1024];
    __shared__ float sB1[64];
    __shared__ float sW2[2048];
    __shared__ float sB2[32];
    __shared__ float sW3[256];
    __shared__ float sB3[8];
    const int tid = threadIdx.x;
    for (int i = tid; i < 160;  i += 256) sE[i]  = emb_table[i];
    for (int i = tid; i < 1024; i += 256) sW1[i] = W1[i];
    for (int i = tid; i < 2048; i += 256) sW2[i] = W2[i];
    for (int i = tid; i < 256;  i += 256) sW3[i] = W3[i];
    if (tid < 64) sB1[tid] = b1[tid];
    if (tid < 32) sB2[tid] = b2[tid];
    if (tid < 8)  sB3[tid] = b3[tid];
    __syncthreads();

    const int n = blockIdx.x * 256 + tid;
    if (n >= N) return;
    const int a = A[n];
    float ae[16];
    #pragma unroll
    for (int i = 0; i < 16; ++i) ae[i] = sE[a * 16 + i];

    float h1[64];
    #pragma unroll
    for (int j = 0; j < 64; ++j) {
        float acc = sB1[j];
        #pragma unroll
        for (int i = 0; i < 16; ++i) acc = fmaf(ae[i], sW1[i * 64 + j], acc);
        h1[j] = silu_f(acc);
    }
    float h2[32];
    #pragma unroll
    for (int j = 0; j < 32; ++j) {
        float acc = sB2[j];
        #pragma unroll 8
        for (int k = 0; k < 64; ++k) acc = fmaf(h1[k], sW2[k * 32 + j], acc);
        h2[j] = silu_f(acc);
    }
    #pragma unroll
    for (int j = 0; j < 8; ++j) {
        float acc = sB3[j];
        #pragma unroll
        for (int k = 0; k < 32; ++k) acc = fmaf(h2[k], sW3[k * 8 + j], acc);
        Ai[n * 8 + j] = acc;
    }
}

// ---------------------------------------------------------------------------
// Edge kernel: 64 edges per 256-thread block.
//   eg  = tid & 63  : edge lane (one edge per lane, shared across 4 waves)
//   sub = tid >> 6  : wave index; wave `sub` owns g-channels [16*sub,16*sub+16)
//                     and v-pair {2*sub, 2*sub+1} in the main contraction.
// LDS (floats): sGbuf 4096 | s_sh 576 | sAs 512 | scratch 8192   = 53.5 KB
//   scratch phase1: Wf2(4096) + Wf3(4096); main: Wf4 chunk(4096); epi: sT(6144)
//   sGbuf: Wf1 staging -> g1 -> g2 -> g3 (layout [k][edge], conflict-free)
// ---------------------------------------------------------------------------
__global__ __launch_bounds__(256, 3) void edge_kernel(
    const float* __restrict__ pos,
    const float* __restrict__ shifts,
    const float* __restrict__ cell,
    const float* __restrict__ Wf1,
    const float* __restrict__ Wf2,
    const float* __restrict__ Wf3,
    const float* __restrict__ Wf4,
    const int*   __restrict__ batch,
    const int*   __restrict__ esrc,
    const int*   __restrict__ edst,
    const float* __restrict__ Aig,
    float* __restrict__ out,
    float* __restrict__ counts,
    int E)
{
    __shared__ __align__(16) float smem[13376];
    float* sGbuf   = smem;          // 4096
    float* s_sh    = smem + 4096;   // 576  : [9][64]
    float* sAs     = smem + 4672;   // 512  : [8][64]
    float* scratch = smem + 5184;   // 8192

    const int tid   = threadIdx.x;
    const int eg    = tid & 63;
    const int sub   = tid >> 6;
    const int vbase = sub * 2;
    const int ch0   = sub * 16;

    // ---- cooperative staging: Wf1 -> sGbuf, Wf2|Wf3 -> scratch
    {
        float4*       g4  = (float4*)sGbuf;
        float4*       sc4 = (float4*)scratch;
        const float4* w1  = (const float4*)Wf1;
        const float4* w2  = (const float4*)Wf2;
        const float4* w3  = (const float4*)Wf3;
        g4[tid] = w1[tid];  // 1024 floats
        #pragma unroll
        for (int q = 0; q < 4; ++q) sc4[q * 256 + tid]        = w2[q * 256 + tid];
        #pragma unroll
        for (int q = 0; q < 4; ++q) sc4[1024 + q * 256 + tid] = w3[q * 256 + tid];
    }

    // ---- per-edge geometry (computed redundantly by each wave for its lane)
    const int  e     = blockIdx.x * 64 + eg;
    const bool valid = e < E;
    const int  ec    = valid ? e : 0;
    const int  src   = esrc[ec];
    const int  dst   = edst[ec];
    const int  bb    = batch[src];
    const float s0 = shifts[ec * 3 + 0], s1 = shifts[ec * 3 + 1], s2 = shifts[ec * 3 + 2];
    const float* cb = cell + bb * 9;
    const float shx = s0 * cb[0] + s1 * cb[3] + s2 * cb[6];
    const float shy = s0 * cb[1] + s1 * cb[4] + s2 * cb[7];
    const float shz = s0 * cb[2] + s1 * cb[5] + s2 * cb[8];
    const float vx = pos[dst * 3 + 0] - pos[src * 3 + 0] + shx;
    const float vy = pos[dst * 3 + 1] - pos[src * 3 + 1] + shy;
    const float vz = pos[dst * 3 + 2] - pos[src * 3 + 2] + shz;
    const float r   = sqrtf(vx * vx + vy * vy + vz * vz);
    const float inv = 1.0f / (r + 1e-9f);
    const float ux = vx * inv, uy = vy * inv, uz = vz * inv;

    if (sub == 0) {
        s_sh[0 * 64 + eg] = 1.0f;
        s_sh[1 * 64 + eg] = S3 * uy;
        s_sh[2 * 64 + eg] = S3 * uz;
        s_sh[3 * 64 + eg] = S3 * ux;
        s_sh[4 * 64 + eg] = S15 * ux * uy;
        s_sh[5 * 64 + eg] = S15 * uy * uz;
        s_sh[6 * 64 + eg] = 0.5f * S5 * (3.0f * uz * uz - 1.0f);
        s_sh[7 * 64 + eg] = S15 * uz * ux;
        s_sh[8 * 64 + eg] = 0.5f * S15 * (ux * ux - uy * uy);
        #pragma unroll
        for (int u = 0; u < 8; ++u) sAs[u * 64 + eg] = Aig[src * 8 + u];
    }
    const float Ad0 = Aig[dst * 8 + vbase];
    const float Ad1 = Aig[dst * 8 + vbase + 1];

    // ---- radial basis: emb[i] = exp(-((r - (i+1)*step)/step)^2) * 4/1.12
    float embv[16];
    {
        const float rs = r * (17.0f / 5.0f);
        #pragma unroll
        for (int i = 0; i < 16; ++i) {
            const float d = rs - (float)(i + 1);
            embv[i] = __expf(-d * d) * (4.0f / 1.12f);
        }
    }

    __syncthreads();

    // ---- g1 = silu(emb @ Wf1): this wave computes 16 channels for its lane's edge
    {
        float ga[16];
        #pragma unroll
        for (int j = 0; j < 16; ++j) ga[j] = 0.0f;
        #pragma unroll
        for (int i = 0; i < 16; ++i) {
            const float ei = embv[i];
            #pragma unroll
            for (int j = 0; j < 16; ++j)
                ga[j] = fmaf(ei, sGbuf[i * 64 + ch0 + j], ga[j]);  // Wf1 broadcast
        }
        __syncthreads();  // all Wf1 reads done before overwrite
        #pragma unroll
        for (int j = 0; j < 16; ++j) sGbuf[(ch0 + j) * 64 + eg] = silu_f(ga[j]);
        __syncthreads();
    }

    // ---- g2 = silu(g1 @ Wf2)
    {
        float acc[16];
        #pragma unroll
        for (int j = 0; j < 16; ++j) acc[j] = 0.0f;
        const float* wf2 = scratch;
        #pragma unroll 4
        for (int k = 0; k < 64; ++k) {
            const float gk = sGbuf[k * 64 + eg];
            #pragma unroll
            for (int j = 0; j < 16; ++j)
                acc[j] = fmaf(gk, wf2[k * 64 + ch0 + j], acc[j]);
        }
        __syncthreads();
        #pragma unroll
        for (int j = 0; j < 16; ++j) sGbuf[(ch0 + j) * 64 + eg] = silu_f(acc[j]);
        __syncthreads();
    }

    // ---- g3 = silu(g2 @ Wf3)
    {
        float acc[16];
        #pragma unroll
        for (int j = 0; j < 16; ++j) acc[j] = 0.0f;
        const float* wf3 = scratch + 4096;
        #pragma unroll 4
        for (int k = 0; k < 64; ++k) {
            const float gk = sGbuf[k * 64 + eg];
            #pragma unroll
            for (int j = 0; j < 16; ++j)
                acc[j] = fmaf(gk, wf3[k * 64 + ch0 + j], acc[j]);
        }
        __syncthreads();
        #pragma unroll
        for (int j = 0; j < 16; ++j) sGbuf[(ch0 + j) * 64 + eg] = silu_f(acc[j]);
        // first main-loop barrier orders these writes vs. reads
    }

    // ---- main contraction: t_l[o] = sum_{k,u,v} g3[k]*As[u]*Ad[v]*Wf4[k,(l,u,v,o)]
    float4 tA[3], tB[3];  // t[l][0..3], t[l][4..7]
    #pragma unroll
    for (int l = 0; l < 3; ++l) {
        tA[l] = make_float4(0.f, 0.f, 0.f, 0.f);
        tB[l] = make_float4(0.f, 0.f, 0.f, 0.f);
    }
    float* sW4 = scratch;  // 64 x 64 chunk
    #pragma unroll
    for (int l = 0; l < 3; ++l) {
        #pragma unroll 1
        for (int u = 0; u < 8; ++u) {
            __syncthreads();  // previous chunk reads done
            {
                const int c = l * 8 + u;
                #pragma unroll
                for (int q = 0; q < 4; ++q) {
                    const int f    = q * 256 + tid;
                    const int row  = f >> 4;
                    const int coff = (f & 15) << 2;
                    *(float4*)&sW4[row * 64 + coff] =
                        *(const float4*)&Wf4[row * 1536 + c * 64 + coff];
                }
            }
            __syncthreads();
            const float su = sAs[u * 64 + eg];
            float4 a00 = make_float4(0.f, 0.f, 0.f, 0.f);
            float4 a01 = a00, a10 = a00, a11 = a00;
            #pragma unroll 4
            for (int k = 0; k < 64; ++k) {
                const float gk = sGbuf[k * 64 + eg];
                const float4* rowp = (const float4*)&sW4[k * 64 + vbase * 8];
                fma4(a00, gk, rowp[0]);  // v = vbase,   o = 0..3
                fma4(a01, gk, rowp[1]);  // v = vbase,   o = 4..7
                fma4(a10, gk, rowp[2]);  // v = vbase+1, o = 0..3
                fma4(a11, gk, rowp[3]);  // v = vbase+1, o = 4..7
            }
            const float c0 = su * Ad0, c1 = su * Ad1;
            fma4(tA[l], c0, a00); fma4(tA[l], c1, a10);
            fma4(tB[l], c0, a01); fma4(tB[l], c1, a11);
        }
    }

    // ---- cross-wave reduction of t partials, then scatter
    __syncthreads();
    float* sT = scratch;  // [4][24][64]
    #pragma unroll
    for (int l = 0; l < 3; ++l) {
        sT[(sub * 24 + l * 8 + 0) * 64 + eg] = tA[l].x;
        sT[(sub * 24 + l * 8 + 1) * 64 + eg] = tA[l].y;
        sT[(sub * 24 + l * 8 + 2) * 64 + eg] = tA[l].z;
        sT[(sub * 24 + l * 8 + 3) * 64 + eg] = tA[l].w;
        sT[(sub * 24 + l * 8 + 4) * 64 + eg] = tB[l].x;
        sT[(sub * 24 + l * 8 + 5) * 64 + eg] = tB[l].y;
        sT[(sub * 24 + l * 8 + 6) * 64 + eg] = tB[l].z;
        sT[(sub * 24 + l * 8 + 7) * 64 + eg] = tB[l].w;
    }
    __syncthreads();

    if (valid) {
        if (sub == 0) atomicAdd(&counts[dst], 1.0f);
        #pragma unroll
        for (int l = 0; l < 3; ++l) {
            const int ml = (l == 0) ? 1 : (l == 1) ? 3 : 5;
            const int ms = (l == 0) ? 0 : (l == 1) ? 1 : 4;
            const int fb = (l == 0) ? 0 : (l == 1) ? 8 : 32;
            #pragma unroll
            for (int op = 0; op < 2; ++op) {
                const int o = vbase + op;  // this wave scatters o-pair {2sub,2sub+1}
                float ts = sT[(0 * 24 + l * 8 + o) * 64 + eg]
                         + sT[(1 * 24 + l * 8 + o) * 64 + eg]
                         + sT[(2 * 24 + l * 8 + o) * 64 + eg]
                         + sT[(3 * 24 + l * 8 + o) * 64 + eg];
                ts *= 0.125f;  // nrm = 1/sqrt(64)
                #pragma unroll
                for (int m = 0; m < ml; ++m) {
                    const float v = ts * s_sh[(ms + m) * 64 + eg];
                    atomicAdd(&out[dst * 72 + fb + o * ml + m], v);
                }
            }
        }
    }
}

// ---------------------------------------------------------------------------
__global__ __launch_bounds__(256) void norm_kernel(float* __restrict__ out,
                                                   const float* __restrict__ counts,
                                                   int total)
{
    const int i = blockIdx.x * 256 + threadIdx.x;
    if (i < total) out[i] = out[i] / fmaxf(counts[i / 72], 1.0f);
}

// ---------------------------------------------------------------------------
extern "C" void kernel_launch(void* const* d_in, const int* in_sizes, int n_in,
                              void* d_out, int out_size, void* d_ws, size_t ws_size,
                              hipStream_t stream)
{
    const float* pos    = (const float*)d_in[0];
    const float* shifts = (const float*)d_in[1];
    const float* cell   = (const float*)d_in[2];
    const float* embt   = (const float*)d_in[3];
    const float* W1  = (const float*)d_in[4];
    const float* b1  = (const float*)d_in[5];
    const float* W2  = (const float*)d_in[6];
    const float* b2  = (const float*)d_in[7];
    const float* W3  = (const float*)d_in[8];
    const float* b3  = (const float*)d_in[9];
    const float* Wf1 = (const float*)d_in[10];
    const float* Wf2 = (const float*)d_in[11];
    const float* Wf3 = (const float*)d_in[12];
    const float* Wf4 = (const float*)d_in[13];
    const int* A     = (const int*)d_in[14];
    const int* batch = (const int*)d_in[15];
    const int* esrc  = (const int*)d_in[16];
    const int* edst  = (const int*)d_in[17];
    float* out = (float*)d_out;

    const int N = in_sizes[0] / 3;
    const int E = in_sizes[16];

    float* Ai     = (float*)d_ws;          // N*8 floats
    float* counts = Ai + (size_t)N * 8;    // N floats

    hipMemsetAsync(d_out, 0, (size_t)out_size * sizeof(float), stream);
    hipMemsetAsync(counts, 0, (size_t)N * sizeof(float), stream);

    node_mlp_kernel<<<(N + 255) / 256, 256, 0, stream>>>(
        embt, W1, b1, W2, b2, W3, b3, A, Ai, N);
    edge_kernel<<<(E + 63) / 64, 256, 0, stream>>>(
        pos, shifts, cell, Wf1, Wf2, Wf3, Wf4, batch, esrc, edst, Ai, out, counts, E);
    norm_kernel<<<(N * 72 + 255) / 256, 256, 0, stream>>>(out, counts, N * 72);
}

// Round 4
// 622.604 us; speedup vs baseline: 1.6877x; 1.6877x over previous
//
#include <hip/hip_runtime.h>

#define S3  1.7320508075688772f
#define S5  2.23606797749979f
#define S15 3.872983346207417f

__device__ __forceinline__ float silu_f(float x) {
    return x / (1.0f + __expf(-x));
}

__device__ __forceinline__ void fma4(float4& a, float s, float4 v) {
    a.x = fmaf(s, v.x, a.x);
    a.y = fmaf(s, v.y, a.y);
    a.z = fmaf(s, v.z, a.z);
    a.w = fmaf(s, v.w, a.w);
}

// ---------------------------------------------------------------------------
// Node MLP: Ai = (silu(silu(emb[A] @ W1 + b1) @ W2 + b2)) @ W3 + b3   (N x 8)
// ---------------------------------------------------------------------------
__global__ __launch_bounds__(256) void node_mlp_kernel(
    const float* __restrict__ emb_table,  // 10x16
    const float* __restrict__ W1, const float* __restrict__ b1,  // 16x64
    const float* __restrict__ W2, const float* __restrict__ b2,  // 64x32
    const float* __restrict__ W3, const float* __restrict__ b3,  // 32x8
    const int*   __restrict__ A,
    float* __restrict__ Ai, int N)
{
    __shared__ float sE[160];
    __shared__ float sW1[1024];
    __shared__ float sB1[64];
    __shared__ float sW2[2048];
    __shared__ float sB2[32];
    __shared__ float sW3[256];
    __shared__ float sB3[8];
    const int tid = threadIdx.x;
    for (int i = tid; i < 160;  i += 256) sE[i]  = emb_table[i];
    for (int i = tid; i < 1024; i += 256) sW1[i] = W1[i];
    for (int i = tid; i < 2048; i += 256) sW2[i] = W2[i];
    for (int i = tid; i < 256;  i += 256) sW3[i] = W3[i];
    if (tid < 64) sB1[tid] = b1[tid];
    if (tid < 32) sB2[tid] = b2[tid];
    if (tid < 8)  sB3[tid] = b3[tid];
    __syncthreads();

    const int n = blockIdx.x * 256 + tid;
    if (n >= N) return;
    const int a = A[n];
    float ae[16];
    #pragma unroll
    for (int i = 0; i < 16; ++i) ae[i] = sE[a * 16 + i];

    float h1[64];
    #pragma unroll
    for (int j = 0; j < 64; ++j) {
        float acc = sB1[j];
        #pragma unroll
        for (int i = 0; i < 16; ++i) acc = fmaf(ae[i], sW1[i * 64 + j], acc);
        h1[j] = silu_f(acc);
    }
    float h2[32];
    #pragma unroll
    for (int j = 0; j < 32; ++j) {
        float acc = sB2[j];
        #pragma unroll 8
        for (int k = 0; k < 64; ++k) acc = fmaf(h1[k], sW2[k * 32 + j], acc);
        h2[j] = silu_f(acc);
    }
    #pragma unroll
    for (int j = 0; j < 8; ++j) {
        float acc = sB3[j];
        #pragma unroll
        for (int k = 0; k < 32; ++k) acc = fmaf(h2[k], sW3[k * 8 + j], acc);
        Ai[n * 8 + j] = acc;
    }
}

// ---------------------------------------------------------------------------
// Counting-sort of edges by dst (replaces fp32 atomic scatter, which was
// atomic-writeback-bound: 365 MB HBM WRITE_SIZE at 373 GB/s for 1000 us).
// ---------------------------------------------------------------------------
__global__ __launch_bounds__(256) void hist_kernel(const int* __restrict__ edst,
                                                   int* __restrict__ counts, int E)
{
    const int e = blockIdx.x * 256 + threadIdx.x;
    if (e < E) atomicAdd(&counts[edst[e]], 1);
}

__global__ __launch_bounds__(1024) void scan_kernel(const int* __restrict__ counts,
                                                    int* __restrict__ offsets,
                                                    int* __restrict__ cursor, int N)
{
    __shared__ int sSum[1024];
    const int tid = threadIdx.x;
    const int per = (N + 1023) / 1024;
    const int base = tid * per;
    int s = 0;
    for (int i = 0; i < per; ++i) {
        const int idx = base + i;
        if (idx < N) s += counts[idx];
    }
    sSum[tid] = s;
    __syncthreads();
    // Hillis-Steele inclusive scan over the 1024 per-thread sums
    for (int off = 1; off < 1024; off <<= 1) {
        const int v = (tid >= off) ? sSum[tid - off] : 0;
        __syncthreads();
        sSum[tid] += v;
        __syncthreads();
    }
    int excl = (tid == 0) ? 0 : sSum[tid - 1];
    for (int i = 0; i < per; ++i) {
        const int idx = base + i;
        if (idx < N) {
            offsets[idx] = excl;
            cursor[idx]  = excl;
            excl += counts[idx];
        }
    }
}

__global__ __launch_bounds__(256) void fill_kernel(const int* __restrict__ edst,
                                                   int* __restrict__ cursor,
                                                   int* __restrict__ order, int E)
{
    const int e = blockIdx.x * 256 + threadIdx.x;
    if (e < E) {
        const int p = atomicAdd(&cursor[edst[e]], 1);
        order[p] = e;
    }
}

// ---------------------------------------------------------------------------
// Edge kernel v3: 64 edges per 256-thread block, scalar-path weights.
//   eg  = tid & 63  : edge lane (one edge per lane, shared across 4 waves)
//   sub = readfirstlane(tid>>6) : wave id (forced wave-uniform so all weight
//         row reads -- Wf1/Wf2/Wf3/Wf4 64-B slices -- become s_load from L2,
//         freeing the LDS pipe and removing all staging barriers).
// LDS (floats): sGbuf 4096 | sAs 512 (both aliased under sT 6144) | s_sh 576
//   total 6720 floats = 26.9 KB (was 53.5 KB).
// ---------------------------------------------------------------------------
__global__ __launch_bounds__(256, 4) void edge_kernel(
    const float* __restrict__ pos,
    const float* __restrict__ shifts,
    const float* __restrict__ cell,
    const float* __restrict__ Wf1,
    const float* __restrict__ Wf2,
    const float* __restrict__ Wf3,
    const float* __restrict__ Wf4,
    const int*   __restrict__ batch,
    const int*   __restrict__ esrc,
    const int*   __restrict__ edst,
    const float* __restrict__ Aig,
    float* __restrict__ ef,
    int E)
{
    __shared__ __align__(16) float smem[6720];
    float* sGbuf = smem;           // 4096 : g layout [k][edge]
    float* sAs   = smem + 4096;    // 512  : [8][64]
    float* sT    = smem;           // 6144 : epilogue exchange (aliases above)
    float* s_sh  = smem + 6144;    // 576  : [9][64]

    const int tid   = threadIdx.x;
    const int eg    = tid & 63;
    const int sub   = __builtin_amdgcn_readfirstlane((int)(threadIdx.x >> 6));
    const int vbase = sub * 2;
    const int ch0   = sub * 16;    // uniform
    const int vb8   = vbase * 8;   // uniform, 64-B aligned slice offset

    // ---- per-edge geometry (computed redundantly by each wave for its lane)
    const int  e     = blockIdx.x * 64 + eg;
    const bool valid = e < E;
    const int  ec    = valid ? e : 0;
    const int  src   = esrc[ec];
    const int  dst   = edst[ec];
    const int  bb    = batch[src];
    const float s0 = shifts[ec * 3 + 0], s1 = shifts[ec * 3 + 1], s2 = shifts[ec * 3 + 2];
    const float* cb = cell + bb * 9;
    const float shx = s0 * cb[0] + s1 * cb[3] + s2 * cb[6];
    const float shy = s0 * cb[1] + s1 * cb[4] + s2 * cb[7];
    const float shz = s0 * cb[2] + s1 * cb[5] + s2 * cb[8];
    const float vx = pos[dst * 3 + 0] - pos[src * 3 + 0] + shx;
    const float vy = pos[dst * 3 + 1] - pos[src * 3 + 1] + shy;
    const float vz = pos[dst * 3 + 2] - pos[src * 3 + 2] + shz;
    const float r   = sqrtf(vx * vx + vy * vy + vz * vz);
    const float inv = 1.0f / (r + 1e-9f);
    const float ux = vx * inv, uy = vy * inv, uz = vz * inv;

    if (sub == 0) {
        s_sh[0 * 64 + eg] = 1.0f;
        s_sh[1 * 64 + eg] = S3 * uy;
        s_sh[2 * 64 + eg] = S3 * uz;
        s_sh[3 * 64 + eg] = S3 * ux;
        s_sh[4 * 64 + eg] = S15 * ux * uy;
        s_sh[5 * 64 + eg] = S15 * uy * uz;
        s_sh[6 * 64 + eg] = 0.5f * S5 * (3.0f * uz * uz - 1.0f);
        s_sh[7 * 64 + eg] = S15 * uz * ux;
        s_sh[8 * 64 + eg] = 0.5f * S15 * (ux * ux - uy * uy);
        #pragma unroll
        for (int u = 0; u < 8; ++u) sAs[u * 64 + eg] = Aig[src * 8 + u];
    }
    const float Ad0 = Aig[dst * 8 + vbase];
    const float Ad1 = Aig[dst * 8 + vbase + 1];

    // ---- radial basis: emb[i] = exp(-((r - (i+1)*step)/step)^2) * 4/1.12
    float embv[16];
    {
        const float rs = r * (17.0f / 5.0f);
        #pragma unroll
        for (int i = 0; i < 16; ++i) {
            const float d = rs - (float)(i + 1);
            embv[i] = __expf(-d * d) * (4.0f / 1.12f);
        }
    }

    // ---- g1 = silu(emb @ Wf1): wave computes channels [ch0,ch0+16) for its edge.
    //      Wf1 rows read as uniform 64-B slices (scalar path), no LDS staging.
    {
        float4 gA = make_float4(0.f, 0.f, 0.f, 0.f), gB = gA, gC = gA, gD = gA;
        #pragma unroll
        for (int i = 0; i < 16; ++i) {
            const float4* wr = (const float4*)(Wf1 + i * 64 + ch0);
            const float ei = embv[i];
            fma4(gA, ei, wr[0]); fma4(gB, ei, wr[1]);
            fma4(gC, ei, wr[2]); fma4(gD, ei, wr[3]);
        }
        sGbuf[(ch0 +  0) * 64 + eg] = silu_f(gA.x);
        sGbuf[(ch0 +  1) * 64 + eg] = silu_f(gA.y);
        sGbuf[(ch0 +  2) * 64 + eg] = silu_f(gA.z);
        sGbuf[(ch0 +  3) * 64 + eg] = silu_f(gA.w);
        sGbuf[(ch0 +  4) * 64 + eg] = silu_f(gB.x);
        sGbuf[(ch0 +  5) * 64 + eg] = silu_f(gB.y);
        sGbuf[(ch0 +  6) * 64 + eg] = silu_f(gB.z);
        sGbuf[(ch0 +  7) * 64 + eg] = silu_f(gB.w);
        sGbuf[(ch0 +  8) * 64 + eg] = silu_f(gC.x);
        sGbuf[(ch0 +  9) * 64 + eg] = silu_f(gC.y);
        sGbuf[(ch0 + 10) * 64 + eg] = silu_f(gC.z);
        sGbuf[(ch0 + 11) * 64 + eg] = silu_f(gC.w);
        sGbuf[(ch0 + 12) * 64 + eg] = silu_f(gD.x);
        sGbuf[(ch0 + 13) * 64 + eg] = silu_f(gD.y);
        sGbuf[(ch0 + 14) * 64 + eg] = silu_f(gD.z);
        sGbuf[(ch0 + 15) * 64 + eg] = silu_f(gD.w);
    }
    __syncthreads();

    // ---- g2 = silu(g1 @ Wf2), g3 = silu(g2 @ Wf3): same pattern
    #pragma unroll 1
    for (int layer = 0; layer < 2; ++layer) {
        const float* __restrict__ Wf = (layer == 0) ? Wf2 : Wf3;
        float4 aA = make_float4(0.f, 0.f, 0.f, 0.f), aB = aA, aC = aA, aD = aA;
        #pragma unroll 4
        for (int k = 0; k < 64; ++k) {
            const float gk = sGbuf[k * 64 + eg];
            const float4* wr = (const float4*)(Wf + k * 64 + ch0);
            fma4(aA, gk, wr[0]); fma4(aB, gk, wr[1]);
            fma4(aC, gk, wr[2]); fma4(aD, gk, wr[3]);
        }
        __syncthreads();  // all reads of previous g done before overwrite
        sGbuf[(ch0 +  0) * 64 + eg] = silu_f(aA.x);
        sGbuf[(ch0 +  1) * 64 + eg] = silu_f(aA.y);
        sGbuf[(ch0 +  2) * 64 + eg] = silu_f(aA.z);
        sGbuf[(ch0 +  3) * 64 + eg] = silu_f(aA.w);
        sGbuf[(ch0 +  4) * 64 + eg] = silu_f(aB.x);
        sGbuf[(ch0 +  5) * 64 + eg] = silu_f(aB.y);
        sGbuf[(ch0 +  6) * 64 + eg] = silu_f(aB.z);
        sGbuf[(ch0 +  7) * 64 + eg] = silu_f(aB.w);
        sGbuf[(ch0 +  8) * 64 + eg] = silu_f(aC.x);
        sGbuf[(ch0 +  9) * 64 + eg] = silu_f(aC.y);
        sGbuf[(ch0 + 10) * 64 + eg] = silu_f(aC.z);
        sGbuf[(ch0 + 11) * 64 + eg] = silu_f(aC.w);
        sGbuf[(ch0 + 12) * 64 + eg] = silu_f(aD.x);
        sGbuf[(ch0 + 13) * 64 + eg] = silu_f(aD.y);
        sGbuf[(ch0 + 14) * 64 + eg] = silu_f(aD.z);
        sGbuf[(ch0 + 15) * 64 + eg] = silu_f(aD.w);
        __syncthreads();
    }

    // ---- main contraction: t_l[o] = sum_{k,u,v} g3[k]*As[u]*Ad[v]*Wf4[k,(l,u,v,o)]
    //      Wf4 row slices [k][ (l*8+u)*64 + vb8 .. +16 ) are wave-uniform 64-B
    //      and 64-B aligned -> scalar loads; NO barriers in this loop.
    float4 tA[3], tB[3];  // t[l][0..3], t[l][4..7]
    #pragma unroll
    for (int l = 0; l < 3; ++l) {
        tA[l] = make_float4(0.f, 0.f, 0.f, 0.f);
        tB[l] = make_float4(0.f, 0.f, 0.f, 0.f);
    }
    #pragma unroll
    for (int l = 0; l < 3; ++l) {
        #pragma unroll 1
        for (int u = 0; u < 8; ++u) {
            const float su = sAs[u * 64 + eg];
            const float* wrow = Wf4 + (l * 8 + u) * 64 + vb8;  // uniform base
            float4 a00 = make_float4(0.f, 0.f, 0.f, 0.f);
            float4 a01 = a00, a10 = a00, a11 = a00;
            #pragma unroll 4
            for (int k = 0; k < 64; ++k) {
                const float gk = sGbuf[k * 64 + eg];
                const float4* wp = (const float4*)(wrow + k * 1536);
                fma4(a00, gk, wp[0]);  // v = vbase,   o = 0..3
                fma4(a01, gk, wp[1]);  // v = vbase,   o = 4..7
                fma4(a10, gk, wp[2]);  // v = vbase+1, o = 0..3
                fma4(a11, gk, wp[3]);  // v = vbase+1, o = 4..7
            }
            const float c0 = su * Ad0, c1 = su * Ad1;
            fma4(tA[l], c0, a00); fma4(tA[l], c1, a10);
            fma4(tB[l], c0, a01); fma4(tB[l], c1, a11);
        }
    }

    // ---- cross-wave reduction of t partials (sT aliases sGbuf/sAs), then store
    __syncthreads();  // all g3/sAs reads done before aliasing writes
    #pragma unroll
    for (int l = 0; l < 3; ++l) {
        sT[(sub * 24 + l * 8 + 0) * 64 + eg] = tA[l].x;
        sT[(sub * 24 + l * 8 + 1) * 64 + eg] = tA[l].y;
        sT[(sub * 24 + l * 8 + 2) * 64 + eg] = tA[l].z;
        sT[(sub * 24 + l * 8 + 3) * 64 + eg] = tA[l].w;
        sT[(sub * 24 + l * 8 + 4) * 64 + eg] = tB[l].x;
        sT[(sub * 24 + l * 8 + 5) * 64 + eg] = tB[l].y;
        sT[(sub * 24 + l * 8 + 6) * 64 + eg] = tB[l].z;
        sT[(sub * 24 + l * 8 + 7) * 64 + eg] = tB[l].w;
    }
    __syncthreads();

    if (valid) {
        float* efe = ef + (size_t)e * 72;
        #pragma unroll
        for (int l = 0; l < 3; ++l) {
            const int ml = (l == 0) ? 1 : (l == 1) ? 3 : 5;
            const int ms = (l == 0) ? 0 : (l == 1) ? 1 : 4;
            const int fb = (l == 0) ? 0 : (l == 1) ? 8 : 32;
            #pragma unroll
            for (int op = 0; op < 2; ++op) {
                const int o = vbase + op;  // this wave stores o-pair {2sub,2sub+1}
                float ts = sT[(0 * 24 + l * 8 + o) * 64 + eg]
                         + sT[(1 * 24 + l * 8 + o) * 64 + eg]
                         + sT[(2 * 24 + l * 8 + o) * 64 + eg]
                         + sT[(3 * 24 + l * 8 + o) * 64 + eg];
                ts *= 0.125f;  // nrm = 1/sqrt(64)
                #pragma unroll
                for (int m = 0; m < ml; ++m)
                    efe[fb + o * ml + m] = ts * s_sh[(ms + m) * 64 + eg];
            }
        }
    }
}

// ---------------------------------------------------------------------------
// Gather: one wave per node; sum dst-sorted edge features, divide by count.
// Writes every element of out (no memset needed). Wave-uniform index loads
// (counts/offsets/order) go scalar via readfirstlane'd wave id.
// ---------------------------------------------------------------------------
__global__ __launch_bounds__(256) void gather_kernel(
    const float* __restrict__ ef,
    const int*   __restrict__ order,
    const int*   __restrict__ offsets,
    const int*   __restrict__ counts,
    float* __restrict__ out, int N)
{
    const int lane = threadIdx.x & 63;
    const int w    = __builtin_amdgcn_readfirstlane((int)(threadIdx.x >> 6));
    const int n    = blockIdx.x * 4 + w;
    if (n >= N) return;
    const int cnt = counts[n];
    const int off = offsets[n];
    float a0 = 0.0f, a1 = 0.0f;
    for (int i = 0; i < cnt; ++i) {
        const int ee = order[off + i];
        const float* p = ef + (size_t)ee * 72;
        a0 += p[lane];
        if (lane < 8) a1 += p[64 + lane];
    }
    const float invc = 1.0f / fmaxf((float)cnt, 1.0f);
    out[n * 72 + lane] = a0 * invc;
    if (lane < 8) out[n * 72 + 64 + lane] = a1 * invc;
}

// ---------------------------------------------------------------------------
extern "C" void kernel_launch(void* const* d_in, const int* in_sizes, int n_in,
                              void* d_out, int out_size, void* d_ws, size_t ws_size,
                              hipStream_t stream)
{
    const float* pos    = (const float*)d_in[0];
    const float* shifts = (const float*)d_in[1];
    const float* cell   = (const float*)d_in[2];
    const float* embt   = (const float*)d_in[3];
    const float* W1  = (const float*)d_in[4];
    const float* b1  = (const float*)d_in[5];
    const float* W2  = (const float*)d_in[6];
    const float* b2  = (const float*)d_in[7];
    const float* W3  = (const float*)d_in[8];
    const float* b3  = (const float*)d_in[9];
    const float* Wf1 = (const float*)d_in[10];
    const float* Wf2 = (const float*)d_in[11];
    const float* Wf3 = (const float*)d_in[12];
    const float* Wf4 = (const float*)d_in[13];
    const int* A     = (const int*)d_in[14];
    const int* batch = (const int*)d_in[15];
    const int* esrc  = (const int*)d_in[16];
    const int* edst  = (const int*)d_in[17];
    float* out = (float*)d_out;

    const int N = in_sizes[0] / 3;
    const int E = in_sizes[16];

    // workspace layout
    float* ef      = (float*)d_ws;                       // E*72 floats (46 MB)
    float* Ai      = ef + (size_t)E * 72;                // N*8 floats
    int*   counts  = (int*)(Ai + (size_t)N * 8);         // N
    int*   offsets = counts + N;                         // N
    int*   cursor  = offsets + N;                        // N
    int*   order   = cursor + N;                         // E

    hipMemsetAsync(counts, 0, (size_t)N * sizeof(int), stream);

    node_mlp_kernel<<<(N + 255) / 256, 256, 0, stream>>>(
        embt, W1, b1, W2, b2, W3, b3, A, Ai, N);
    hist_kernel<<<(E + 255) / 256, 256, 0, stream>>>(edst, counts, E);
    scan_kernel<<<1, 1024, 0, stream>>>(counts, offsets, cursor, N);
    fill_kernel<<<(E + 255) / 256, 256, 0, stream>>>(edst, cursor, order, E);
    edge_kernel<<<(E + 63) / 64, 256, 0, stream>>>(
        pos, shifts, cell, Wf1, Wf2, Wf3, Wf4, batch, esrc, edst, Ai, ef, E);
    gather_kernel<<<(N + 3) / 4, 256, 0, stream>>>(
        ef, order, offsets, counts, out, N);
}

// Round 13
// 368.253 us; speedup vs baseline: 2.8533x; 1.6907x over previous
//
#include <hip/hip_runtime.h>

#define S3  1.7320508075688772f
#define S5  2.23606797749979f
#define S15 3.872983346207417f

typedef __attribute__((ext_vector_type(8))) short bf16x8;
typedef __attribute__((ext_vector_type(4))) float f32x4;

__device__ __forceinline__ float silu_f(float x) {
    return x / (1.0f + __expf(-x));
}

__device__ __forceinline__ void fma4(float4& a, float s, float4 v) {
    a.x = fmaf(s, v.x, a.x);
    a.y = fmaf(s, v.y, a.y);
    a.z = fmaf(s, v.z, a.z);
    a.w = fmaf(s, v.w, a.w);
}

// split fp32 -> bf16 hi + bf16 lo (truncation; lo captures the residual)
__device__ __forceinline__ void bf16_split(float v, short& hi, short& lo) {
    unsigned int b = __float_as_uint(v);
    unsigned short h = (unsigned short)(b >> 16);
    float hf = __uint_as_float(((unsigned int)h) << 16);
    float r = v - hf;
    hi = (short)h;
    lo = (short)(__float_as_uint(r) >> 16);
}

// ---------------------------------------------------------------------------
// Node MLP: Ai = (silu(silu(emb[A] @ W1 + b1) @ W2 + b2)) @ W3 + b3   (N x 8)
// ---------------------------------------------------------------------------
__global__ __launch_bounds__(256) void node_mlp_kernel(
    const float* __restrict__ emb_table,
    const float* __restrict__ W1, const float* __restrict__ b1,
    const float* __restrict__ W2, const float* __restrict__ b2,
    const float* __restrict__ W3, const float* __restrict__ b3,
    const int*   __restrict__ A,
    float* __restrict__ Ai, int N)
{
    __shared__ float sE[160];
    __shared__ float sW1[1024];
    __shared__ float sB1[64];
    __shared__ float sW2[2048];
    __shared__ float sB2[32];
    __shared__ float sW3[256];
    __shared__ float sB3[8];
    const int tid = threadIdx.x;
    for (int i = tid; i < 160;  i += 256) sE[i]  = emb_table[i];
    for (int i = tid; i < 1024; i += 256) sW1[i] = W1[i];
    for (int i = tid; i < 2048; i += 256) sW2[i] = W2[i];
    for (int i = tid; i < 256;  i += 256) sW3[i] = W3[i];
    if (tid < 64) sB1[tid] = b1[tid];
    if (tid < 32) sB2[tid] = b2[tid];
    if (tid < 8)  sB3[tid] = b3[tid];
    __syncthreads();

    const int n = blockIdx.x * 256 + tid;
    if (n >= N) return;
    const int a = A[n];
    float ae[16];
    #pragma unroll
    for (int i = 0; i < 16; ++i) ae[i] = sE[a * 16 + i];

    float h1[64];
    #pragma unroll
    for (int j = 0; j < 64; ++j) {
        float acc = sB1[j];
        #pragma unroll
        for (int i = 0; i < 16; ++i) acc = fmaf(ae[i], sW1[i * 64 + j], acc);
        h1[j] = silu_f(acc);
    }
    float h2[32];
    #pragma unroll
    for (int j = 0; j < 32; ++j) {
        float acc = sB2[j];
        #pragma unroll 8
        for (int k = 0; k < 64; ++k) acc = fmaf(h1[k], sW2[k * 32 + j], acc);
        h2[j] = silu_f(acc);
    }
    #pragma unroll
    for (int j = 0; j < 8; ++j) {
        float acc = sB3[j];
        #pragma unroll
        for (int k = 0; k < 32; ++k) acc = fmaf(h2[k], sW3[k * 8 + j], acc);
        Ai[n * 8 + j] = acc;
    }
}

// ---------------------------------------------------------------------------
// Counting sort of edges by dst (no fp32 atomics anywhere downstream).
// ---------------------------------------------------------------------------
__global__ __launch_bounds__(256) void hist_kernel(const int* __restrict__ edst,
                                                   int* __restrict__ counts, int E)
{
    const int e = blockIdx.x * 256 + threadIdx.x;
    if (e < E) atomicAdd(&counts[edst[e]], 1);
}

__global__ __launch_bounds__(1024) void scan_kernel(const int* __restrict__ counts,
                                                    int* __restrict__ offsets,
                                                    int* __restrict__ cursor, int N)
{
    __shared__ int sSum[1024];
    const int tid = threadIdx.x;
    const int per = (N + 1023) / 1024;
    const int base = tid * per;
    int s = 0;
    for (int i = 0; i < per; ++i) {
        const int idx = base + i;
        if (idx < N) s += counts[idx];
    }
    sSum[tid] = s;
    __syncthreads();
    for (int off = 1; off < 1024; off <<= 1) {
        const int v = (tid >= off) ? sSum[tid - off] : 0;
        __syncthreads();
        sSum[tid] += v;
        __syncthreads();
    }
    int excl = (tid == 0) ? 0 : sSum[tid - 1];
    for (int i = 0; i < per; ++i) {
        const int idx = base + i;
        if (idx < N) {
            offsets[idx] = excl;
            cursor[idx]  = excl;
            excl += counts[idx];
        }
    }
}

__global__ __launch_bounds__(256) void fill_kernel(const int* __restrict__ edst,
                                                   int* __restrict__ cursor,
                                                   int* __restrict__ order, int E)
{
    const int e = blockIdx.x * 256 + threadIdx.x;
    if (e < E) {
        const int p = atomicAdd(&cursor[edst[e]], 1);
        order[p] = e;
    }
}

// ---------------------------------------------------------------------------
// Wf4 precompute: split to bf16 hi/lo and transpose into MFMA A-frag order.
//   w4hi/lo[c][kb][vo][j] = split(Wf4[8*kb+j][c*64+vo]),  c=0..23, kb=0..7,
//   vo=0..63, j=0..7.   (A = Wf4^T chunk: A[vo][k], frag-linear per chunk)
// ---------------------------------------------------------------------------
__global__ __launch_bounds__(256) void split_wf4_kernel(
    const float* __restrict__ Wf4,
    unsigned short* __restrict__ w4hi,
    unsigned short* __restrict__ w4lo)
{
    const int idx = blockIdx.x * 256 + threadIdx.x;   // 24*4096 total
    const int c   = idx >> 12;
    const int rem = idx & 4095;
    const int j   = rem & 7;
    const int kvo = rem >> 3;
    const int kb  = kvo >> 6;
    const int vo  = kvo & 63;
    const float v = Wf4[(8 * kb + j) * 1536 + c * 64 + vo];
    short hi, lo;
    bf16_split(v, hi, lo);
    w4hi[idx] = (unsigned short)hi;
    w4lo[idx] = (unsigned short)lo;
}

// ---------------------------------------------------------------------------
// Edge kernel v4c: MFMA (split-bf16, 3 terms) for the 64x64x64 per-chunk GEMM.
//   wave sub owns vo-rows [16sub,16sub+16); N = all 64 edges; 24 chunks (l,u).
//   B-frags (g3) live in registers for the whole block. A staged LDS per chunk.
//   Output: COMPRESSED rank-1 features ef[e][36] = { t[24] (pre-scaled), sh[9] }.
// LDS float map (total 12096 f = 48.4 KB):
//   [0,4096)      sA: chunk A, hi ushort[4096] | lo ushort[4096]
//                 (alias: prologue fp32 g buffer [64k][64e])
//   [4096,4608)   sAs[8][64]      [4608,5120) sAd[8][64]
//   [5120,5696)   s_sh[9][64]
//   [5696,9792)   sGbf: g3 split, hi ushort[4096] | lo ushort[4096]
//   [5696,12096)  sT[4 vslot][64 e][25]  (stride 25: gcd(25,32)=1 -> 2-way
//                 bank aliasing = free; stride 24 would be 16-way conflict)
// ---------------------------------------------------------------------------
__global__ __launch_bounds__(256) void edge_kernel(
    const float* __restrict__ pos,
    const float* __restrict__ shifts,
    const float* __restrict__ cell,
    const float* __restrict__ Wf1,
    const float* __restrict__ Wf2,
    const float* __restrict__ Wf3,
    const unsigned short* __restrict__ w4hi,
    const unsigned short* __restrict__ w4lo,
    const int*   __restrict__ batch,
    const int*   __restrict__ esrc,
    const int*   __restrict__ edst,
    const float* __restrict__ Aig,
    float* __restrict__ ef,
    int E)
{
    __shared__ __align__(16) float smem[12096];
    float* sGbuf = smem;                      // prologue fp32 g
    float* sAs   = smem + 4096;
    float* sAd   = smem + 4608;
    float* s_sh  = smem + 5120;
    float* sT    = smem + 5696;
    unsigned short* sAhiU = (unsigned short*)smem;          // chunk A hi
    unsigned short* sAloU = sAhiU + 4096;                   // chunk A lo
    unsigned short* gHi   = (unsigned short*)(smem + 5696); // g3 hi
    unsigned short* gLo   = gHi + 4096;                     // g3 lo

    const int tid  = threadIdx.x;
    const int eg   = tid & 63;                 // lane / edge index
    const int sub  = __builtin_amdgcn_readfirstlane((int)(threadIdx.x >> 6));
    const int ch0  = sub * 16;                 // uniform: this wave's g channels
    const int h    = eg >> 4;                  // lane k-block group
    const int c15  = eg & 15;                  // lane row/col within frag

    // ---- per-edge geometry
    const int  e     = blockIdx.x * 64 + eg;
    const bool valid = e < E;
    const int  ec    = valid ? e : 0;
    const int  src   = esrc[ec];
    const int  dst   = edst[ec];
    const int  bb    = batch[src];
    const float s0 = shifts[ec * 3 + 0], s1 = shifts[ec * 3 + 1], s2 = shifts[ec * 3 + 2];
    const float* cb = cell + bb * 9;
    const float shx = s0 * cb[0] + s1 * cb[3] + s2 * cb[6];
    const float shy = s0 * cb[1] + s1 * cb[4] + s2 * cb[7];
    const float shz = s0 * cb[2] + s1 * cb[5] + s2 * cb[8];
    const float vx = pos[dst * 3 + 0] - pos[src * 3 + 0] + shx;
    const float vy = pos[dst * 3 + 1] - pos[src * 3 + 1] + shy;
    const float vz = pos[dst * 3 + 2] - pos[src * 3 + 2] + shz;
    const float r   = sqrtf(vx * vx + vy * vy + vz * vz);
    const float inv = 1.0f / (r + 1e-9f);
    const float ux = vx * inv, uy = vy * inv, uz = vz * inv;

    if (sub == 0) {
        s_sh[0 * 64 + eg] = 1.0f;
        s_sh[1 * 64 + eg] = S3 * uy;
        s_sh[2 * 64 + eg] = S3 * uz;
        s_sh[3 * 64 + eg] = S3 * ux;
        s_sh[4 * 64 + eg] = S15 * ux * uy;
        s_sh[5 * 64 + eg] = S15 * uy * uz;
        s_sh[6 * 64 + eg] = 0.5f * S5 * (3.0f * uz * uz - 1.0f);
        s_sh[7 * 64 + eg] = S15 * uz * ux;
        s_sh[8 * 64 + eg] = 0.5f * S15 * (ux * ux - uy * uy);
        #pragma unroll
        for (int u = 0; u < 8; ++u) sAs[u * 64 + eg] = Aig[src * 8 + u];
    }
    if (sub == 1) {
        #pragma unroll
        for (int u = 0; u < 8; ++u) sAd[u * 64 + eg] = Aig[dst * 8 + u];
    }

    // ---- radial basis
    float embv[16];
    {
        const float rs = r * (17.0f / 5.0f);
        #pragma unroll
        for (int i = 0; i < 16; ++i) {
            const float d = rs - (float)(i + 1);
            embv[i] = __expf(-d * d) * (4.0f / 1.12f);
        }
    }

    // ---- g1 = silu(emb @ Wf1): wave computes channels [ch0,ch0+16) for edge eg.
    {
        float4 gA = make_float4(0.f, 0.f, 0.f, 0.f), gB = gA, gC = gA, gD = gA;
        #pragma unroll
        for (int i = 0; i < 16; ++i) {
            const float4* wr = (const float4*)(Wf1 + i * 64 + ch0);
            const float ei = embv[i];
            fma4(gA, ei, wr[0]); fma4(gB, ei, wr[1]);
            fma4(gC, ei, wr[2]); fma4(gD, ei, wr[3]);
        }
        float gq[16] = {gA.x,gA.y,gA.z,gA.w, gB.x,gB.y,gB.z,gB.w,
                        gC.x,gC.y,gC.z,gC.w, gD.x,gD.y,gD.z,gD.w};
        #pragma unroll
        for (int j = 0; j < 16; ++j) sGbuf[(ch0 + j) * 64 + eg] = silu_f(gq[j]);
    }
    __syncthreads();

    // ---- g2 = silu(g1 @ Wf2)
    {
        float4 aA = make_float4(0.f, 0.f, 0.f, 0.f), aB = aA, aC = aA, aD = aA;
        #pragma unroll 4
        for (int k = 0; k < 64; ++k) {
            const float gk = sGbuf[k * 64 + eg];
            const float4* wr = (const float4*)(Wf2 + k * 64 + ch0);
            fma4(aA, gk, wr[0]); fma4(aB, gk, wr[1]);
            fma4(aC, gk, wr[2]); fma4(aD, gk, wr[3]);
        }
        __syncthreads();
        float gq[16] = {aA.x,aA.y,aA.z,aA.w, aB.x,aB.y,aB.z,aB.w,
                        aC.x,aC.y,aC.z,aC.w, aD.x,aD.y,aD.z,aD.w};
        #pragma unroll
        for (int j = 0; j < 16; ++j) sGbuf[(ch0 + j) * 64 + eg] = silu_f(gq[j]);
        __syncthreads();
    }

    // ---- g3 = silu(g2 @ Wf3), written split-bf16 directly into frag layout
    {
        float4 aA = make_float4(0.f, 0.f, 0.f, 0.f), aB = aA, aC = aA, aD = aA;
        #pragma unroll 4
        for (int k = 0; k < 64; ++k) {
            const float gk = sGbuf[k * 64 + eg];
            const float4* wr = (const float4*)(Wf3 + k * 64 + ch0);
            fma4(aA, gk, wr[0]); fma4(aB, gk, wr[1]);
            fma4(aC, gk, wr[2]); fma4(aD, gk, wr[3]);
        }
        float gq[16] = {aA.x,aA.y,aA.z,aA.w, aB.x,aB.y,aB.z,aB.w,
                        aC.x,aC.y,aC.z,aC.w, aD.x,aD.y,aD.z,aD.w};
        __syncthreads();   // all sGbuf (g2) reads complete
        #pragma unroll
        for (int half = 0; half < 2; ++half) {
            bf16x8 ph, pl;
            #pragma unroll
            for (int j = 0; j < 8; ++j) {
                const float v = silu_f(gq[half * 8 + j]);
                short hi16, lo16;
                bf16_split(v, hi16, lo16);
                ph[j] = hi16;
                pl[j] = lo16;
            }
            const int kb = 2 * sub + half;     // k-block this thread owns
            *(bf16x8*)(gHi + (kb * 64 + eg) * 8) = ph;
            *(bf16x8*)(gLo + (kb * 64 + eg) * 8) = pl;
        }
    }
    __syncthreads();

    // ---- load B-frags (g3) to registers: same for all waves; [nt*2+s]
    bf16x8 Bh[8], Bl[8];
    #pragma unroll
    for (int nt = 0; nt < 4; ++nt)
        #pragma unroll
        for (int s = 0; s < 2; ++s) {
            const int off = ((4 * s + h) * 64 + 16 * nt + c15) * 8;
            Bh[nt * 2 + s] = *(const bf16x8*)(gHi + off);
            Bl[nt * 2 + s] = *(const bf16x8*)(gLo + off);
        }

    // hoist Ad: this lane's v = 2*sub + (h>>1), per nt edge 16nt+c15
    const int vlane = 2 * sub + (h >> 1);
    float AdR[4];
    #pragma unroll
    for (int nt = 0; nt < 4; ++nt) AdR[nt] = sAd[vlane * 64 + 16 * nt + c15];

    // ---- chunk loop: cc = l*8 + u ; A staged in LDS, prefetch next chunk
    float t[16];   // [nt][j]  (e = 16nt+c15, o = 4*(h&1)+j), this lane's v only
    uint4 vh0, vh1, vl0, vl1;
    {
        const unsigned short* gh = w4hi;       // chunk 0
        const unsigned short* gl = w4lo;
        vh0 = *(const uint4*)(gh + tid * 8);
        vh1 = *(const uint4*)(gh + 2048 + tid * 8);
        vl0 = *(const uint4*)(gl + tid * 8);
        vl1 = *(const uint4*)(gl + 2048 + tid * 8);
    }

    #pragma unroll 1
    for (int cc = 0; cc < 24; ++cc) {
        const int l = cc >> 3;
        const int u = cc & 7;
        if (u == 0) {
            #pragma unroll
            for (int i = 0; i < 16; ++i) t[i] = 0.0f;
        }

        __syncthreads();                       // prev chunk's sA reads done
        *(uint4*)(sAhiU + tid * 8)        = vh0;
        *(uint4*)(sAhiU + 2048 + tid * 8) = vh1;
        *(uint4*)(sAloU + tid * 8)        = vl0;
        *(uint4*)(sAloU + 2048 + tid * 8) = vl1;
        __syncthreads();                       // sA visible

        if (cc + 1 < 24) {                     // prefetch next chunk (hides L2 latency
            const unsigned short* gh = w4hi + (cc + 1) * 4096;   //  under the MFMA phase)
            const unsigned short* gl = w4lo + (cc + 1) * 4096;
            vh0 = *(const uint4*)(gh + tid * 8);
            vh1 = *(const uint4*)(gh + 2048 + tid * 8);
            vl0 = *(const uint4*)(gl + tid * 8);
            vl1 = *(const uint4*)(gl + 2048 + tid * 8);
        }

        // MFMA: D[16 vo x 64 e] for this wave's vo rows, 3 split terms
        f32x4 acc[4];
        #pragma unroll
        for (int nt = 0; nt < 4; ++nt) acc[nt] = (f32x4){0.f, 0.f, 0.f, 0.f};
        #pragma unroll
        for (int s = 0; s < 2; ++s) {
            const int abase = ((4 * s + h) * 64 + 16 * sub + c15) * 8;
            const bf16x8 ah = *(const bf16x8*)(sAhiU + abase);
            const bf16x8 al = *(const bf16x8*)(sAloU + abase);
            #pragma unroll
            for (int nt = 0; nt < 4; ++nt) {
                acc[nt] = __builtin_amdgcn_mfma_f32_16x16x32_bf16(ah, Bh[nt * 2 + s], acc[nt], 0, 0, 0);
                acc[nt] = __builtin_amdgcn_mfma_f32_16x16x32_bf16(ah, Bl[nt * 2 + s], acc[nt], 0, 0, 0);
                acc[nt] = __builtin_amdgcn_mfma_f32_16x16x32_bf16(al, Bh[nt * 2 + s], acc[nt], 0, 0, 0);
            }
        }

        // epilogue: t[nt][j] += As[u][e] * Ad[v][e] * D
        #pragma unroll
        for (int nt = 0; nt < 4; ++nt) {
            const float coef = sAs[u * 64 + 16 * nt + c15] * AdR[nt];
            #pragma unroll
            for (int j = 0; j < 4; ++j)
                t[nt * 4 + j] = fmaf(coef, acc[nt][j], t[nt * 4 + j]);
        }

        if (u == 7) {
            // reduce over the wave's v-pair (partner lane = lane ^ 32), store
            #pragma unroll
            for (int i = 0; i < 16; ++i) t[i] += __shfl_xor(t[i], 32);
            if (h < 2) {
                #pragma unroll
                for (int nt = 0; nt < 4; ++nt)
                    #pragma unroll
                    for (int j = 0; j < 4; ++j)
                        sT[(sub * 64 + 16 * nt + c15) * 25 + l * 8 + 4 * h + j] = t[nt * 4 + j];
            }
        }
    }
    __syncthreads();

    // ---- final: sum the 4 v-pair slots, scale; store COMPRESSED {t[24], sh[9]}
    if (valid) {
        float* efe = ef + (size_t)e * 36;
        #pragma unroll
        for (int q = 0; q < 6; ++q) {
            const int idx = sub * 6 + q;       // 0..23 = l*8+o
            float ssum = sT[(0 * 64 + eg) * 25 + idx] + sT[(1 * 64 + eg) * 25 + idx]
                       + sT[(2 * 64 + eg) * 25 + idx] + sT[(3 * 64 + eg) * 25 + idx];
            efe[idx] = ssum * 0.125f;          // nrm = 1/sqrt(64)
        }
        if (sub == 0) {
            #pragma unroll
            for (int m = 0; m < 9; ++m) efe[24 + m] = s_sh[m * 64 + eg];
        }
    }
}

// ---------------------------------------------------------------------------
// Gather: one wave per node; reconstruct out[f] = sum_e t[idx(f)]*sh[msh(f)],
// divide by count. Reads 33 floats/edge instead of 72 (rank-1 compression).
// ---------------------------------------------------------------------------
__global__ __launch_bounds__(256) void gather_kernel(
    const float* __restrict__ ef,
    const int*   __restrict__ order,
    const int*   __restrict__ offsets,
    const int*   __restrict__ counts,
    float* __restrict__ out, int N)
{
    const int lane = threadIdx.x & 63;
    const int w    = threadIdx.x >> 6;
    const int n    = blockIdx.x * 4 + w;
    if (n >= N) return;

    // lane -> (t-slot, sh-slot) for out col f = lane (layout: l0 8x1 | l1 8x3 | l2 8x5)
    int idx0, msh0;
    if (lane < 8)       { idx0 = lane; msh0 = 0; }
    else if (lane < 32) { const int q = (lane - 8) / 3,  m = (lane - 8) % 3;
                          idx0 = 8 + q;  msh0 = 1 + m; }
    else                { const int q = (lane - 32) / 5, m = (lane - 32) % 5;
                          idx0 = 16 + q; msh0 = 4 + m; }
    // second col f2 = 64 + lane (lane < 8): always in l2 region
    const int q1 = (32 + lane) / 5, m1 = (32 + lane) % 5;
    const int idx1 = 16 + q1, msh1 = 4 + m1;

    const int cnt = counts[n];
    const int off = offsets[n];
    float a0 = 0.0f, a1 = 0.0f;
    for (int i = 0; i < cnt; ++i) {
        const int ee = order[off + i];
        const float* p = ef + (size_t)ee * 36;
        a0 = fmaf(p[idx0], p[24 + msh0], a0);
        if (lane < 8) a1 = fmaf(p[idx1], p[24 + msh1], a1);
    }
    const float invc = 1.0f / fmaxf((float)cnt, 1.0f);
    out[n * 72 + lane] = a0 * invc;
    if (lane < 8) out[n * 72 + 64 + lane] = a1 * invc;
}

// ---------------------------------------------------------------------------
extern "C" void kernel_launch(void* const* d_in, const int* in_sizes, int n_in,
                              void* d_out, int out_size, void* d_ws, size_t ws_size,
                              hipStream_t stream)
{
    const float* pos    = (const float*)d_in[0];
    const float* shifts = (const float*)d_in[1];
    const float* cell   = (const float*)d_in[2];
    const float* embt   = (const float*)d_in[3];
    const float* W1  = (const float*)d_in[4];
    const float* b1  = (const float*)d_in[5];
    const float* W2  = (const float*)d_in[6];
    const float* b2  = (const float*)d_in[7];
    const float* W3  = (const float*)d_in[8];
    const float* b3  = (const float*)d_in[9];
    const float* Wf1 = (const float*)d_in[10];
    const float* Wf2 = (const float*)d_in[11];
    const float* Wf3 = (const float*)d_in[12];
    const float* Wf4 = (const float*)d_in[13];
    const int* A     = (const int*)d_in[14];
    const int* batch = (const int*)d_in[15];
    const int* esrc  = (const int*)d_in[16];
    const int* edst  = (const int*)d_in[17];
    float* out = (float*)d_out;

    const int N = in_sizes[0] / 3;
    const int E = in_sizes[16];

    // workspace layout (~24.9 MB total)
    float* ef      = (float*)d_ws;                       // E*36 floats (23.0 MB)
    float* Ai      = ef + (size_t)E * 36;                // N*8 floats
    int*   counts  = (int*)(Ai + (size_t)N * 8);         // N
    int*   offsets = counts + N;                         // N
    int*   cursor  = offsets + N;                        // N
    int*   order   = cursor + N;                         // E
    unsigned short* w4hi = (unsigned short*)(order + E); // 24*4096
    unsigned short* w4lo = w4hi + 24 * 4096;             // 24*4096

    hipMemsetAsync(counts, 0, (size_t)N * sizeof(int), stream);

    split_wf4_kernel<<<384, 256, 0, stream>>>(Wf4, w4hi, w4lo);
    node_mlp_kernel<<<(N + 255) / 256, 256, 0, stream>>>(
        embt, W1, b1, W2, b2, W3, b3, A, Ai, N);
    hist_kernel<<<(E + 255) / 256, 256, 0, stream>>>(edst, counts, E);
    scan_kernel<<<1, 1024, 0, stream>>>(counts, offsets, cursor, N);
    fill_kernel<<<(E + 255) / 256, 256, 0, stream>>>(edst, cursor, order, E);
    edge_kernel<<<(E + 63) / 64, 256, 0, stream>>>(
        pos, shifts, cell, Wf1, Wf2, Wf3, w4hi, w4lo, batch, esrc, edst, Ai, ef, E);
    gather_kernel<<<(N + 3) / 4, 256, 0, stream>>>(
        ef, order, offsets, counts, out, N);
}